// Round 6
// baseline (237.830 us; speedup 1.0000x reference)
//
#include <hip/hip_runtime.h>
#include <hip/hip_bf16.h>

// Sparse conv2d as bf16 implicit GEMM, 256(M) x 224(N) x 64(K).
// A (densified weights) read DIRECT from global (L2-resident) into registers;
// B (im2col pixels) double-buffered in LDS; one phase per K-tile.
// x:[32,256,56,56]f32  w_vals:[256,64,3,3]f32  w_idx:[256,64]i32  out:[32,256,56,56]f32
// ws: Wd bf16 [9][256 o][256 c] (1,179,648 B) | Xp bf16 [32][58][58][256] (55,115,776 B)
// Grid 448 tiles of 224 px (3136 = 14*224: tiles never cross b or h-group).

typedef __attribute__((ext_vector_type(8))) short bf16x8;
typedef __attribute__((ext_vector_type(4))) float f32x4;

#define WD_BYTES 1179648
#define XP_BYTES 55115776
#define WS_NEED  (WD_BYTES + XP_BYTES)

// ---------------- preprocessing ----------------

// Block o: zero Wd[:, o, :] (only writer of row o), then scatter its 64 taps.
__global__ __launch_bounds__(64) void scatter_w(
    const float* __restrict__ wv, const int* __restrict__ widx,
    __hip_bfloat16* __restrict__ wd)
{
    int o = blockIdx.x, j = threadIdx.x;
#pragma unroll
    for (int k = 0; k < 9; ++k)
        reinterpret_cast<float2*>(wd + (size_t)k * 65536 + o * 256)[j] = float2{0.f, 0.f};
    __syncthreads();
    int cin = widx[o * 64 + j];
    const float* src = wv + (size_t)(o * 64 + j) * 9;
#pragma unroll
    for (int k = 0; k < 9; ++k)
        wd[(size_t)k * 65536 + o * 256 + cin] = __float2bfloat16(src[k]);
}

// Block (b,h): transpose [256 c][56 w] fp32 -> bf16 NHWC padded row h+1,
// plus halo borders (w=0,57 of this row; full rows 0/57 when h==0/55).
__global__ __launch_bounds__(256) void x_to_nhwc(
    const float* __restrict__ x, __hip_bfloat16* __restrict__ xp)
{
    int blk = blockIdx.x;
    int b = blk / 56, h = blk - (blk / 56) * 56;
    __shared__ __hip_bfloat16 tile[56][264];
    int c = threadIdx.x;
    const float* src = x + ((size_t)(b * 256 + c)) * 3136 + h * 56;
    float vals[56];
#pragma unroll
    for (int i = 0; i < 14; ++i) {
        float4 v = *reinterpret_cast<const float4*>(src + i * 4);
        vals[i*4+0] = v.x; vals[i*4+1] = v.y; vals[i*4+2] = v.z; vals[i*4+3] = v.w;
    }
#pragma unroll
    for (int w = 0; w < 56; ++w) tile[w][c] = __float2bfloat16(vals[w]);

    char* rowb = (char*)xp + (((size_t)b * 58 + (h + 1)) * 58) * 512;
    int tid = threadIdx.x;
    if (tid < 64)        reinterpret_cast<double*>(rowb)[tid] = 0.0;
    else if (tid < 128)  *reinterpret_cast<double*>(rowb + 57 * 512 + (tid - 64) * 8) = 0.0;
    if (h == 0) {
        char* r0 = (char*)xp + (((size_t)b * 58 + 0) * 58) * 512;
        for (int i = tid; i < 58 * 64; i += 256) reinterpret_cast<double*>(r0)[i] = 0.0;
    }
    if (h == 55) {
        char* r57 = (char*)xp + (((size_t)b * 58 + 57) * 58) * 512;
        for (int i = tid; i < 58 * 64; i += 256) reinterpret_cast<double*>(r57)[i] = 0.0;
    }

    __syncthreads();
    char* obase = (char*)xp + (((size_t)b * 58 + (h + 1)) * 58) * 512;
#pragma unroll
    for (int k = 0; k < 7; ++k) {
        int i = threadIdx.x + k * 256;
        int w = i >> 5, cc = i & 31;
        bf16x8 v = *reinterpret_cast<const bf16x8*>(&tile[w][cc * 8]);
        *reinterpret_cast<bf16x8*>(obase + (size_t)(w + 1) * 512 + cc * 16) = v;
    }
}

// ---------------- GEMM: A-direct, B via LDS, 1 phase per K-tile ----------------

__device__ __forceinline__ void gload_lds16(const void* g, void* l) {
    __builtin_amdgcn_global_load_lds(
        (const __attribute__((address_space(1))) void*)g,
        (__attribute__((address_space(3))) void*)l, 16, 0, 0);
}

// B-tile [224 rows][128 B] in buf BB (28672 B each); instr J covers rows
// J*64 + wid*8 + lane>>3 (J=3: wid<4 only).
template<int BB, int J>
__device__ __forceinline__ void stage_b(const char* xpB, char* smem, int wid,
                                        int pbJ, int boff) {
    gload_lds16(xpB + pbJ + boff,
                smem + BB * 28672 + (J * 64 + wid * 8) * 128);
}

// B half QN (QN==0: 4 frags, QN==1: 3), rows wc*112 + QN*64 + ni*16.
template<int BB, int QN, int NF>
__device__ __forceinline__ void load_b(const char* smem, int wc, int a_rb,
                                       int xq0, int xq1, bf16x8 (&bfr)[NF][2]) {
#pragma unroll
    for (int ni = 0; ni < (QN ? 3 : 4); ++ni) {
        int base = BB * 28672 + (wc * 112 + QN * 64 + ni * 16) * 128 + a_rb;
        bfr[ni][0] = *(const bf16x8*)(smem + base + xq0);
        bfr[ni][1] = *(const bf16x8*)(smem + base + xq1);
    }
}

__device__ __forceinline__ int pixoff(int p) {   // byte offset of pixel p in Xp
    int b = p / 3136; int r = p - b * 3136;
    int h = r / 56;   int w = r - h * 56;
    return ((b * 58 + h + 1) * 58 + (w + 1)) * 512;
}

__device__ __forceinline__ int aoff_t(int t) {
    return (t >> 2) * 131072 + (t & 3) * 128;
}
__device__ __forceinline__ int boff_t(int t) {   // relative to padded pixoff
    int k9 = t >> 2; int kh = k9 / 3; int kw = k9 - 3 * kh;
    return ((kh - 1) * 58 + (kw - 1)) * 512 + (t & 3) * 128;
}

#define BAR() __builtin_amdgcn_s_barrier()
#define VMCNT0() asm volatile("s_waitcnt vmcnt(0)" ::: "memory")

// One K-tile phase. U = current LDS buffer (t&1). Consumes afc (A regs for
// tile t), prefetches afn (A for tNext) and stages B(tNext) into buf 1-U.
template<int U>
__device__ __forceinline__ void phase(
    const char* wdB, const char* xpB, char* smem,
    int wid, int wc, int a_rb, int xq0, int xq1,
    int pb0, int pb1, int pb2, int pb3,
    const char* pAlane,              // wdB + wr*64*512 + (lane&15)*512 + (lane>>4)*16
    int tNext,
    bf16x8 (&afc)[4][2], bf16x8 (&afn)[4][2],
    f32x4 (&acc)[4][7])
{
    VMCNT0();     // drains B-stage(t) + A(t) loads (issued a full phase ago)
    BAR();        // all waves: buf U complete; reads of buf 1-U finished
    const int bn = boff_t(tNext);
    stage_b<1-U,0>(xpB, smem, wid, pb0, bn);
    stage_b<1-U,1>(xpB, smem, wid, pb1, bn);
    stage_b<1-U,2>(xpB, smem, wid, pb2, bn);
    if (wid < 4) stage_b<1-U,3>(xpB, smem, wid, pb3, bn);
    // A prefetch for tNext (global, L2-hot, fully coalesced 64B per o-row)
    const char* pA = pAlane + aoff_t(tNext);
#pragma unroll
    for (int mi = 0; mi < 4; ++mi) {
        afn[mi][0] = *(const bf16x8*)(pA + mi * 8192);
        afn[mi][1] = *(const bf16x8*)(pA + mi * 8192 + 64);
    }
    // B fragments for current tile
    bf16x8 b0[4][2], b1[3][2];
    load_b<U,0,4>(smem, wc, a_rb, xq0, xq1, b0);
    load_b<U,1,3>(smem, wc, a_rb, xq0, xq1, b1);
    // 56-MFMA cluster
    __builtin_amdgcn_s_setprio(1);
#pragma unroll
    for (int mi = 0; mi < 4; ++mi) {
#pragma unroll
        for (int ni = 0; ni < 4; ++ni)
#pragma unroll
            for (int s = 0; s < 2; ++s)
                acc[mi][ni] = __builtin_amdgcn_mfma_f32_16x16x32_bf16(
                    afc[mi][s], b0[ni][s], acc[mi][ni], 0, 0, 0);
#pragma unroll
        for (int ni = 0; ni < 3; ++ni)
#pragma unroll
            for (int s = 0; s < 2; ++s)
                acc[mi][4+ni] = __builtin_amdgcn_mfma_f32_16x16x32_bf16(
                    afc[mi][s], b1[ni][s], acc[mi][4+ni], 0, 0, 0);
    }
    __builtin_amdgcn_s_setprio(0);
}

__global__ __launch_bounds__(512, 2) void sparse_conv_mfma224(
    const __hip_bfloat16* __restrict__ wd, const __hip_bfloat16* __restrict__ xp,
    float* __restrict__ out)
{
    extern __shared__ char smem[];
    const char* wdB = (const char*)wd;
    const char* xpB = (const char*)xp;

    const int nt = blockIdx.x;            // 448 N-tiles of 224 px
    const int t = threadIdx.x;
    const int lane = t & 63, wid = t >> 6;
    const int wr = wid >> 1, wc = wid & 1;   // 4M x 2N wave grid

    // B staging constants (pre-swizzled global source, linear LDS dest)
    const int axor = (((lane & 7) ^ (lane >> 3)) * 16);
    const int prow = wid * 8 + (lane >> 3);
    const int pb0 = pixoff(nt * 224 +   0 + prow) + axor;
    const int pb1 = pixoff(nt * 224 +  64 + prow) + axor;
    const int pb2 = pixoff(nt * 224 + 128 + prow) + axor;
    const int pb3 = (wid < 4) ? (pixoff(nt * 224 + 192 + prow) + axor) : 0;

    // B fragment-read constants (XOR matches staging pre-swizzle)
    const int a_rb = (lane & 15) * 128;
    const int xq0 = (((lane >> 4)) ^ (lane & 7)) * 16;
    const int xq1 = ((4 + (lane >> 4)) ^ (lane & 7)) * 16;

    // A direct-load per-lane base: row = wr*64 + (lane&15), k-chunk (lane>>4)*16
    const char* pAlane = wdB + (wr * 64 + (lane & 15)) * 512 + (lane >> 4) * 16;

    f32x4 acc[4][7] = {};
    bf16x8 afA[4][2], afB[4][2];

    // ---- prologue: stage B(0) into buf0; load A(0) into afA ----
    {
        const int b0 = boff_t(0);
        stage_b<0,0>(xpB, smem, wid, pb0, b0);
        stage_b<0,1>(xpB, smem, wid, pb1, b0);
        stage_b<0,2>(xpB, smem, wid, pb2, b0);
        if (wid < 4) stage_b<0,3>(xpB, smem, wid, pb3, b0);
        const char* pA = pAlane + aoff_t(0);
#pragma unroll
        for (int mi = 0; mi < 4; ++mi) {
            afA[mi][0] = *(const bf16x8*)(pA + mi * 8192);
            afA[mi][1] = *(const bf16x8*)(pA + mi * 8192 + 64);
        }
    }

    // ---- main loop: 18 iterations x 2 K-tiles (36 total) ----
    for (int it = 0; it < 18; ++it) {
        int t1 = 2 * it + 1;                          // < 36
        int t2 = 2 * it + 2; if (t2 == 36) t2 = 0;    // wrapped dead prefetch
        phase<0>(wdB, xpB, smem, wid, wc, a_rb, xq0, xq1,
                 pb0, pb1, pb2, pb3, pAlane, t1, afA, afB, acc);
        phase<1>(wdB, xpB, smem, wid, wc, a_rb, xq0, xq1,
                 pb0, pb1, pb2, pb3, pAlane, t2, afB, afA, acc);
    }

    // ---- epilogue: out[b][o][px] ----
#pragma unroll
    for (int n = 0; n < 7; ++n) {
        int p0 = nt * 224 + wc * 112 + n * 16;   // wave-uniform; 16 | 3136
        int pb = p0 / 3136;
        int rem0 = p0 - pb * 3136;
#pragma unroll
        for (int m = 0; m < 4; ++m) {
            int o = wr * 64 + m * 16 + (lane >> 4) * 4;
            float* dst = out + ((size_t)(pb * 256 + o)) * 3136 + rem0 + (lane & 15);
#pragma unroll
            for (int r = 0; r < 4; ++r) dst[(size_t)r * 3136] = acc[m][n][r];
        }
    }
}

// ---------------- fallback (ws too small) ----------------

__global__ __launch_bounds__(256) void sparse_conv_direct(
    const float* __restrict__ x, const float* __restrict__ wv,
    const int* __restrict__ widx, float* __restrict__ out)
{
    const int bid = blockIdx.x;
    const int b = bid >> 8, o = bid & 255;
    const int tid = threadIdx.x;
    __shared__ float plane[58 * 60];
    const int rt = tid >> 3, ct = tid & 7;
    const int r0 = rt * 2, c0 = ct * 7;
    const bool active = (rt < 28);
    float acc[2][7];
#pragma unroll
    for (int i = 0; i < 2; ++i)
#pragma unroll
        for (int c = 0; c < 7; ++c) acc[i][c] = 0.f;
    const float* xb = x + (size_t)b * 256 * 3136;
    const int* idxp = widx + o * 64;
    const float* wp0 = wv + (size_t)o * 64 * 9;
    for (int j = 0; j < 64; ++j) {
        const int cin = idxp[j];
        const float* src = xb + cin * 3136;
        __syncthreads();
        for (int i = tid; i < 58 * 58; i += 256) {
            const int r = i / 58, c = i - r * 58;
            const int h = r - 1, w = c - 1;
            float v = 0.f;
            if ((unsigned)h < 56u && (unsigned)w < 56u) v = src[h * 56 + w];
            plane[r * 60 + c] = v;
        }
        float wreg[9];
#pragma unroll
        for (int k = 0; k < 9; ++k) wreg[k] = wp0[j * 9 + k];
        __syncthreads();
        if (active) {
            float rows[4][9];
#pragma unroll
            for (int dr = 0; dr < 4; ++dr)
#pragma unroll
                for (int cc = 0; cc < 9; ++cc)
                    rows[dr][cc] = plane[(r0 + dr) * 60 + (c0 + cc)];
#pragma unroll
            for (int i = 0; i < 2; ++i)
#pragma unroll
                for (int cc = 0; cc < 7; ++cc) {
                    float s = acc[i][cc];
#pragma unroll
                    for (int kh = 0; kh < 3; ++kh)
#pragma unroll
                        for (int kw = 0; kw < 3; ++kw)
                            s += rows[i + kh][cc + kw] * wreg[kh * 3 + kw];
                    acc[i][cc] = s;
                }
        }
    }
    if (active) {
        float* op = out + (size_t)bid * 3136;
#pragma unroll
        for (int i = 0; i < 2; ++i)
#pragma unroll
            for (int cc = 0; cc < 7; ++cc)
                op[(r0 + i) * 56 + (c0 + cc)] = acc[i][cc];
    }
}

extern "C" void kernel_launch(void* const* d_in, const int* in_sizes, int n_in,
                              void* d_out, int out_size, void* d_ws, size_t ws_size,
                              hipStream_t stream) {
    const float* x    = (const float*)d_in[0];
    const float* wv   = (const float*)d_in[1];
    const int*   widx = (const int*)d_in[2];
    float* out = (float*)d_out;
    (void)in_sizes; (void)n_in; (void)out_size;

    if (ws_size < (size_t)WS_NEED) {
        sparse_conv_direct<<<dim3(32 * 256), dim3(256), 0, stream>>>(x, wv, widx, out);
        return;
    }

    __hip_bfloat16* wd = (__hip_bfloat16*)d_ws;
    __hip_bfloat16* xp = (__hip_bfloat16*)((char*)d_ws + WD_BYTES);

    scatter_w<<<dim3(256), dim3(64), 0, stream>>>(wv, widx, wd);
    x_to_nhwc<<<dim3(32 * 56), dim3(256), 0, stream>>>(x, xp);

    (void)hipFuncSetAttribute((const void*)sparse_conv_mfma224,
                              hipFuncAttributeMaxDynamicSharedMemorySize, 57344);
    sparse_conv_mfma224<<<dim3(448), dim3(512), 57344, stream>>>(wd, xp, out);
}